// Round 1
// baseline (1245.554 us; speedup 1.0000x reference)
//
#include <hip/hip_runtime.h>
#include <hip/hip_bf16.h>
#include <cmath>

#define BB 8
#define PP 16384
#define CC 256
#define NCLUS 8
#define BPROWS (BB*PP)

#define KC 32
#define TILE 128

// D[p][j] = sum_k S[p][k] * W[j][k] + bias[j]   (W row-major (256,256))
__global__ __launch_bounds__(256) void gemm_bt(const float* __restrict__ S,
    const float* __restrict__ W, const float* __restrict__ bias,
    float* __restrict__ D) {
  __shared__ float Sl[KC][132];
  __shared__ float Wl[KC][132];
  const int p0 = blockIdx.x * TILE;
  const int j0 = blockIdx.y * TILE;
  const int t  = threadIdx.x;
  const int tx = t & 15;   // j micro index
  const int ty = t >> 4;   // p micro index
  float acc[8][8];
  #pragma unroll
  for (int i = 0; i < 8; ++i)
    #pragma unroll
    for (int j = 0; j < 8; ++j) acc[i][j] = 0.0f;

  for (int kc = 0; kc < CC; kc += KC) {
    __syncthreads();
    #pragma unroll
    for (int i = 0; i < 4; ++i) {
      int idx = t + i*256;      // 0..1023
      int row = idx >> 3;       // 0..127
      int q   = idx & 7;        // float4 within 32-wide k chunk
      float4 v = *(const float4*)&S[(size_t)(p0+row)*CC + kc + q*4];
      Sl[q*4+0][row] = v.x; Sl[q*4+1][row] = v.y;
      Sl[q*4+2][row] = v.z; Sl[q*4+3][row] = v.w;
      float4 w = *(const float4*)&W[(size_t)(j0+row)*CC + kc + q*4];
      Wl[q*4+0][row] = w.x; Wl[q*4+1][row] = w.y;
      Wl[q*4+2][row] = w.z; Wl[q*4+3][row] = w.w;
    }
    __syncthreads();
    #pragma unroll
    for (int k = 0; k < KC; ++k) {
      float4 a0 = *(const float4*)&Sl[k][ty*8];
      float4 a1 = *(const float4*)&Sl[k][ty*8+4];
      float4 b0 = *(const float4*)&Wl[k][tx*8];
      float4 b1 = *(const float4*)&Wl[k][tx*8+4];
      float a[8] = {a0.x,a0.y,a0.z,a0.w,a1.x,a1.y,a1.z,a1.w};
      float b[8] = {b0.x,b0.y,b0.z,b0.w,b1.x,b1.y,b1.z,b1.w};
      #pragma unroll
      for (int i = 0; i < 8; ++i)
        #pragma unroll
        for (int j = 0; j < 8; ++j)
          acc[i][j] = fmaf(a[i], b[j], acc[i][j]);
    }
  }
  #pragma unroll
  for (int i = 0; i < 8; ++i) {
    int p = p0 + ty*8 + i;
    int j = j0 + tx*8;
    float4 o0, o1;
    o0.x = acc[i][0] + bias[j+0]; o0.y = acc[i][1] + bias[j+1];
    o0.z = acc[i][2] + bias[j+2]; o0.w = acc[i][3] + bias[j+3];
    o1.x = acc[i][4] + bias[j+4]; o1.y = acc[i][5] + bias[j+5];
    o1.z = acc[i][6] + bias[j+6]; o1.w = acc[i][7] + bias[j+7];
    *(float4*)&D[(size_t)p*CC + j]     = o0;
    *(float4*)&D[(size_t)p*CC + j + 4] = o1;
  }
}

// rnorm[row] = 1 / max(||nodes[row,:]||, 1e-12)
__global__ __launch_bounds__(256) void rownorm(const float* __restrict__ nodes,
                                               float* __restrict__ rnorm) {
  const int lane = threadIdx.x & 63;
  const int wid  = (blockIdx.x * 256 + threadIdx.x) >> 6;  // 8192 waves
  for (int row = wid; row < BPROWS; row += 8192) {
    float4 v = *(const float4*)&nodes[(size_t)row*CC + lane*4];
    float s = v.x*v.x + v.y*v.y + v.z*v.z + v.w*v.w;
    #pragma unroll
    for (int off = 32; off; off >>= 1) s += __shfl_xor(s, off);
    if (lane == 0) rnorm[row] = 1.0f / fmaxf(sqrtf(s), 1e-12f);
  }
}

__global__ void init_centers(const float* __restrict__ nodes, float* __restrict__ centers) {
  const int idx[8] = {0, 2340, 4680, 7021, 9361, 11702, 14042, 16383};
  int b = blockIdx.x >> 3, k = blockIdx.x & 7;
  int c = threadIdx.x;
  centers[(size_t)(b*NCLUS + k)*CC + c] = nodes[((size_t)b*PP + idx[k])*CC + c];
}

// cnorm = centers / max(||centers||, eps); also zero acc & counts for next pass
__global__ __launch_bounds__(256) void center_norm(const float* __restrict__ centers,
    float* __restrict__ cnorm, float* __restrict__ acc, float* __restrict__ counts) {
  int row = blockIdx.x;           // 0..63 = (b,k)
  int t = threadIdx.x;
  float v = centers[(size_t)row*CC + t];
  float s = v*v;
  #pragma unroll
  for (int off = 32; off; off >>= 1) s += __shfl_xor(s, off);
  __shared__ float ps[4];
  if ((t & 63) == 0) ps[t >> 6] = s;
  __syncthreads();
  float tot = ps[0] + ps[1] + ps[2] + ps[3];
  cnorm[(size_t)row*CC + t] = v / fmaxf(sqrtf(tot), 1e-12f);
  acc[(size_t)row*CC + t] = 0.0f;
  if (t == 0) counts[row] = 0.0f;
}

// per point: argmax_k dot(nodes[p], cnorm[k]); accumulate nodes row + count into cluster
__global__ __launch_bounds__(256) void assign_acc(const float* __restrict__ nodes,
    const float* __restrict__ cnorm, float* __restrict__ acc, float* __restrict__ counts) {
  __shared__ float cn[NCLUS][CC];
  __shared__ float la[NCLUS][CC];
  __shared__ float lc[NCLUS];
  const int b  = blockIdx.x >> 7;
  const int pb = blockIdx.x & 127;     // 128 points per block
  const int t  = threadIdx.x;
  for (int i = t; i < NCLUS*CC; i += 256) {
    ((float*)cn)[i] = cnorm[(size_t)b*NCLUS*CC + i];
    ((float*)la)[i] = 0.0f;
  }
  if (t < NCLUS) lc[t] = 0.0f;
  __syncthreads();
  const int wave = t >> 6, lane = t & 63;
  for (int i = 0; i < 32; ++i) {
    int p = pb*128 + wave*32 + i;
    size_t off = ((size_t)b*PP + p)*CC;
    float4 v = *(const float4*)&nodes[off + lane*4];
    float sim[8];
    #pragma unroll
    for (int k = 0; k < NCLUS; ++k) {
      float4 c4 = *(const float4*)&cn[k][lane*4];
      sim[k] = v.x*c4.x + v.y*c4.y + v.z*c4.z + v.w*c4.w;
    }
    #pragma unroll
    for (int o = 32; o; o >>= 1)
      #pragma unroll
      for (int k = 0; k < NCLUS; ++k) sim[k] += __shfl_xor(sim[k], o);
    int best = 0; float bs = sim[0];
    #pragma unroll
    for (int k = 1; k < NCLUS; ++k) if (sim[k] > bs) { bs = sim[k]; best = k; }
    atomicAdd(&la[best][lane*4+0], v.x);
    atomicAdd(&la[best][lane*4+1], v.y);
    atomicAdd(&la[best][lane*4+2], v.z);
    atomicAdd(&la[best][lane*4+3], v.w);
    if (lane == 0) atomicAdd(&lc[best], 1.0f);
  }
  __syncthreads();
  for (int i = t; i < NCLUS*CC; i += 256) atomicAdd(&acc[(size_t)b*NCLUS*CC + i], ((float*)la)[i]);
  if (t < NCLUS) atomicAdd(&counts[b*NCLUS + t], lc[t]);
}

__global__ void update_centers(const float* __restrict__ acc, const float* __restrict__ counts,
                               float* __restrict__ centers) {
  int row = blockIdx.x; int t = threadIdx.x;
  centers[(size_t)row*CC + t] = acc[(size_t)row*CC + t] / fmaxf(counts[row], 1.0f);
}

// t = softmax(10*sim) @ centers + F_p   (written in-place over nodes)
__global__ __launch_bounds__(256) void final_fuse(float* __restrict__ nodes,
    const float* __restrict__ F_p, const float* __restrict__ cnorm,
    const float* __restrict__ centers, const float* __restrict__ rnorm) {
  __shared__ float cn[NCLUS][CC];
  __shared__ float ce[NCLUS][CC];
  const int b  = blockIdx.x >> 7;
  const int pb = blockIdx.x & 127;
  const int t  = threadIdx.x;
  for (int i = t; i < NCLUS*CC; i += 256) {
    ((float*)cn)[i] = cnorm[(size_t)b*NCLUS*CC + i];
    ((float*)ce)[i] = centers[(size_t)b*NCLUS*CC + i];
  }
  __syncthreads();
  const int wave = t >> 6, lane = t & 63;
  for (int i = 0; i < 32; ++i) {
    int p = pb*128 + wave*32 + i;
    size_t off = ((size_t)b*PP + p)*CC;
    float4 v = *(const float4*)&nodes[off + lane*4];
    float rn = rnorm[b*PP + p];
    float sim[8];
    #pragma unroll
    for (int k = 0; k < NCLUS; ++k) {
      float4 c4 = *(const float4*)&cn[k][lane*4];
      sim[k] = v.x*c4.x + v.y*c4.y + v.z*c4.z + v.w*c4.w;
    }
    #pragma unroll
    for (int o = 32; o; o >>= 1)
      #pragma unroll
      for (int k = 0; k < NCLUS; ++k) sim[k] += __shfl_xor(sim[k], o);
    // softmax over 8 with temp 10 (sim scaled by rnorm to get true cosine sim)
    float m = -1e30f;
    #pragma unroll
    for (int k = 0; k < NCLUS; ++k) { sim[k] = sim[k] * rn * 10.0f; m = fmaxf(m, sim[k]); }
    float w[NCLUS], sw = 0.0f;
    #pragma unroll
    for (int k = 0; k < NCLUS; ++k) { w[k] = __expf(sim[k] - m); sw += w[k]; }
    float inv = 1.0f / sw;
    float4 cl = {0.0f, 0.0f, 0.0f, 0.0f};
    #pragma unroll
    for (int k = 0; k < NCLUS; ++k) {
      float wk = w[k] * inv;
      float4 c4 = *(const float4*)&ce[k][lane*4];
      cl.x = fmaf(wk, c4.x, cl.x); cl.y = fmaf(wk, c4.y, cl.y);
      cl.z = fmaf(wk, c4.z, cl.z); cl.w = fmaf(wk, c4.w, cl.w);
    }
    float4 f4 = *(const float4*)&F_p[off + lane*4];
    cl.x += f4.x; cl.y += f4.y; cl.z += f4.z; cl.w += f4.w;
    *(float4*)&nodes[off + lane*4] = cl;
  }
}

extern "C" void kernel_launch(void* const* d_in, const int* in_sizes, int n_in,
                              void* d_out, int out_size, void* d_ws, size_t ws_size,
                              hipStream_t stream) {
  const float* F_p      = (const float*)d_in[0];
  const float* proj_w   = (const float*)d_in[1];
  const float* proj_b   = (const float*)d_in[2];
  const float* refine_w = (const float*)d_in[3];
  const float* refine_b = (const float*)d_in[4];
  float* out = (float*)d_out;

  char* ws = (char*)d_ws;
  float* nodes   = (float*)ws;                                  // 134217728 B
  float* rnorm   = (float*)(ws + (size_t)BPROWS*CC*sizeof(float));
  float* centers = rnorm + BPROWS;
  float* cnorm   = centers + BB*NCLUS*CC;
  float* acc     = cnorm + BB*NCLUS*CC;
  float* counts  = acc + BB*NCLUS*CC;

  dim3 gg(BPROWS/TILE, CC/TILE);
  gemm_bt<<<gg, 256, 0, stream>>>(F_p, proj_w, proj_b, nodes);
  rownorm<<<2048, 256, 0, stream>>>(nodes, rnorm);
  init_centers<<<64, 256, 0, stream>>>(nodes, centers);
  for (int it = 0; it < 3; ++it) {
    center_norm<<<64, 256, 0, stream>>>(centers, cnorm, acc, counts);
    assign_acc<<<1024, 256, 0, stream>>>(nodes, cnorm, acc, counts);
    update_centers<<<64, 256, 0, stream>>>(acc, counts, centers);
  }
  center_norm<<<64, 256, 0, stream>>>(centers, cnorm, acc, counts);
  final_fuse<<<1024, 256, 0, stream>>>(nodes, F_p, cnorm, centers, rnorm);
  gemm_bt<<<gg, 256, 0, stream>>>(nodes, refine_w, refine_b, out);
}

// Round 2
// 735.694 us; speedup vs baseline: 1.6930x; 1.6930x over previous
//
#include <hip/hip_runtime.h>
#include <hip/hip_bf16.h>
#include <cmath>

#define BB 8
#define PP 16384
#define CC 256
#define NCLUS 8
#define BPROWS (BB*PP)
#define KC 32
#define TILE 128

typedef unsigned int uint;
typedef unsigned short ushort;

__device__ __forceinline__ float bflo(uint u){ return __uint_as_float(u << 16); }
__device__ __forceinline__ float bfhi(uint u){ return __uint_as_float(u & 0xffff0000u); }
__device__ __forceinline__ ushort f2bf(float x){ __hip_bfloat16 h = __float2bfloat16(x); return *(ushort*)&h; }

// D[p][j] = sum_k S[p][k] * W[j][k] + bias[j]   (W row-major (256,256))
// SBF: S is bf16 (row-major 256); OBF: D written as bf16.
template<bool SBF, bool OBF>
__global__ __launch_bounds__(256) void gemm_bt(const void* __restrict__ Sv,
    const float* __restrict__ W, const float* __restrict__ bias,
    void* __restrict__ Dv) {
  __shared__ float Sl[KC][132];
  __shared__ float Wl[KC][132];
  const int p0 = blockIdx.x * TILE;
  const int j0 = blockIdx.y * TILE;
  const int t  = threadIdx.x;
  const int tx = t & 15;   // j micro index
  const int ty = t >> 4;   // p micro index
  float acc[8][8];
  #pragma unroll
  for (int i = 0; i < 8; ++i)
    #pragma unroll
    for (int j = 0; j < 8; ++j) acc[i][j] = 0.0f;

  for (int kc = 0; kc < CC; kc += KC) {
    __syncthreads();
    if constexpr (SBF) {
      const ushort* S = (const ushort*)Sv;
      #pragma unroll
      for (int i = 0; i < 2; ++i) {
        int idx = t + i*256;      // 0..511
        int row = idx >> 2;       // 0..127
        int q   = idx & 3;        // 8-col group
        uint4 u = *(const uint4*)(S + (size_t)(p0+row)*CC + kc + q*8);
        Sl[q*8+0][row] = bflo(u.x); Sl[q*8+1][row] = bfhi(u.x);
        Sl[q*8+2][row] = bflo(u.y); Sl[q*8+3][row] = bfhi(u.y);
        Sl[q*8+4][row] = bflo(u.z); Sl[q*8+5][row] = bfhi(u.z);
        Sl[q*8+6][row] = bflo(u.w); Sl[q*8+7][row] = bfhi(u.w);
      }
    } else {
      const float* S = (const float*)Sv;
      #pragma unroll
      for (int i = 0; i < 4; ++i) {
        int idx = t + i*256;
        int row = idx >> 3;
        int q   = idx & 7;
        float4 v = *(const float4*)&S[(size_t)(p0+row)*CC + kc + q*4];
        Sl[q*4+0][row] = v.x; Sl[q*4+1][row] = v.y;
        Sl[q*4+2][row] = v.z; Sl[q*4+3][row] = v.w;
      }
    }
    #pragma unroll
    for (int i = 0; i < 4; ++i) {
      int idx = t + i*256;
      int row = idx >> 3;
      int q   = idx & 7;
      float4 w = *(const float4*)&W[(size_t)(j0+row)*CC + kc + q*4];
      Wl[q*4+0][row] = w.x; Wl[q*4+1][row] = w.y;
      Wl[q*4+2][row] = w.z; Wl[q*4+3][row] = w.w;
    }
    __syncthreads();
    #pragma unroll
    for (int k = 0; k < KC; ++k) {
      float4 a0 = *(const float4*)&Sl[k][ty*8];
      float4 a1 = *(const float4*)&Sl[k][ty*8+4];
      float4 b0 = *(const float4*)&Wl[k][tx*8];
      float4 b1 = *(const float4*)&Wl[k][tx*8+4];
      float a[8] = {a0.x,a0.y,a0.z,a0.w,a1.x,a1.y,a1.z,a1.w};
      float b[8] = {b0.x,b0.y,b0.z,b0.w,b1.x,b1.y,b1.z,b1.w};
      #pragma unroll
      for (int i = 0; i < 8; ++i)
        #pragma unroll
        for (int j = 0; j < 8; ++j)
          acc[i][j] = fmaf(a[i], b[j], acc[i][j]);
    }
  }
  #pragma unroll
  for (int i = 0; i < 8; ++i) {
    int p = p0 + ty*8 + i;
    int j = j0 + tx*8;
    float o[8];
    #pragma unroll
    for (int jj = 0; jj < 8; ++jj) o[jj] = acc[i][jj] + bias[j+jj];
    if constexpr (OBF) {
      uint4 ov;
      ov.x = (uint)f2bf(o[0]) | ((uint)f2bf(o[1]) << 16);
      ov.y = (uint)f2bf(o[2]) | ((uint)f2bf(o[3]) << 16);
      ov.z = (uint)f2bf(o[4]) | ((uint)f2bf(o[5]) << 16);
      ov.w = (uint)f2bf(o[6]) | ((uint)f2bf(o[7]) << 16);
      *(uint4*)((ushort*)Dv + (size_t)p*CC + j) = ov;
    } else {
      float* D = (float*)Dv;
      *(float4*)&D[(size_t)p*CC + j]     = make_float4(o[0],o[1],o[2],o[3]);
      *(float4*)&D[(size_t)p*CC + j + 4] = make_float4(o[4],o[5],o[6],o[7]);
    }
  }
}

// rnorm[row] = 1 / max(||row||, 1e-12)  computed from bf16 nodes
__global__ __launch_bounds__(256) void rownorm_bf(const ushort* __restrict__ nbf,
                                                  float* __restrict__ rnorm) {
  const int lane = threadIdx.x & 63;
  const int wid  = (blockIdx.x * 256 + threadIdx.x) >> 6;  // 8192 waves
  for (int row = wid; row < BPROWS; row += 8192) {
    uint2 u = *(const uint2*)(nbf + (size_t)row*CC + lane*4);
    float v0 = bflo(u.x), v1 = bfhi(u.x), v2 = bflo(u.y), v3 = bfhi(u.y);
    float s = v0*v0 + v1*v1 + v2*v2 + v3*v3;
    #pragma unroll
    for (int o = 32; o; o >>= 1) s += __shfl_xor(s, o);
    if (lane == 0) rnorm[row] = 1.0f / fmaxf(sqrtf(s), 1e-12f);
  }
}

__global__ void init_centers(const ushort* __restrict__ nbf, float* __restrict__ centers) {
  const int idx[8] = {0, 2340, 4680, 7021, 9361, 11702, 14042, 16383};
  int b = blockIdx.x >> 3, k = blockIdx.x & 7;
  int c = threadIdx.x;
  centers[(size_t)(b*NCLUS + k)*CC + c] =
      __uint_as_float(((uint)nbf[((size_t)b*PP + idx[k])*CC + c]) << 16);
}

// centers -> cnorm ; zero acc slots + counts
__global__ __launch_bounds__(256) void center_norm_init(const float* __restrict__ centers,
    float* __restrict__ cnorm, float* __restrict__ accs, float* __restrict__ counts) {
  const int row = blockIdx.x;   // 0..63
  const int t = threadIdx.x;
  float c = centers[(size_t)row*CC + t];
  float s2 = c*c;
  #pragma unroll
  for (int o = 32; o; o >>= 1) s2 += __shfl_xor(s2, o);
  __shared__ float ps[4];
  if ((t & 63) == 0) ps[t >> 6] = s2;
  __syncthreads();
  float tot = ps[0] + ps[1] + ps[2] + ps[3];
  cnorm[(size_t)row*CC + t] = c * (1.0f / fmaxf(sqrtf(tot), 1e-12f));
  #pragma unroll
  for (int s = 0; s < 8; ++s) accs[((size_t)s*64 + row)*CC + t] = 0.0f;
  if (t == 0) counts[row] = 0.0f;
}

// sims[k] = dot(bf16 row, cnL[k])  -- cnL reads are wave-broadcast (conflict-free)
__device__ __forceinline__ void compute_sims(const uint4* __restrict__ rp,
                                             const float (*cnL)[CC], float* sims) {
  #pragma unroll
  for (int k = 0; k < 8; ++k) sims[k] = 0.0f;
  #pragma unroll 4
  for (int q = 0; q < 32; ++q) {
    uint4 u = rp[q];
    float v0 = bflo(u.x), v1 = bfhi(u.x), v2 = bflo(u.y), v3 = bfhi(u.y);
    float v4 = bflo(u.z), v5 = bfhi(u.z), v6 = bflo(u.w), v7 = bfhi(u.w);
    #pragma unroll
    for (int k = 0; k < 8; ++k) {
      const float4* c = (const float4*)&cnL[k][q*8];
      float4 c0 = c[0], c1 = c[1];
      sims[k] += v0*c0.x + v1*c0.y + v2*c0.z + v3*c0.w
               + v4*c1.x + v5*c1.y + v6*c1.z + v7*c1.w;
    }
  }
}

// phase1: 1 point/thread argmax (no shuffles); phase2: column-parallel accumulate
__global__ __launch_bounds__(256) void assign_acc2(const ushort* __restrict__ nbf,
    const float* __restrict__ cnorm, float* __restrict__ accs, float* __restrict__ counts) {
  __shared__ float cnL[NCLUS][CC];
  __shared__ float accL[2][NCLUS][CC];
  __shared__ int assignL[256];
  __shared__ int cntL[NCLUS];
  const int t = threadIdx.x;
  const int b = blockIdx.x >> 6;          // batch (64 blocks per batch)
  for (int i = t; i < NCLUS*CC; i += 256)
    ((float*)cnL)[i] = cnorm[(size_t)b*NCLUS*CC + i];
  if (t < NCLUS) cntL[t] = 0;
  __syncthreads();
  // ---- phase 1: assignment
  const size_t p = (size_t)blockIdx.x*256 + t;
  float sims[8];
  compute_sims((const uint4*)(nbf + p*CC), cnL, sims);
  int best = 0; float bs = sims[0];
  #pragma unroll
  for (int k = 1; k < 8; ++k) if (sims[k] > bs) { bs = sims[k]; best = k; }
  assignL[t] = best;
  atomicAdd(&cntL[best], 1);
  __syncthreads();
  // ---- phase 2: column-parallel accumulation (L2-hot re-read)
  const int c2   = t & 127;               // column pair c2*2, c2*2+1
  const int half = t >> 7;                // which 128 points
  float a0[8] = {0,0,0,0,0,0,0,0}, a1[8] = {0,0,0,0,0,0,0,0};
  const ushort* base = nbf + ((size_t)blockIdx.x*256 + half*128)*CC;
  #pragma unroll 4
  for (int i = 0; i < 128; ++i) {
    int a = __builtin_amdgcn_readfirstlane(assignL[half*128 + i]);  // wave-uniform
    uint u = *(const uint*)(base + (size_t)i*CC + c2*2);
    float lo = bflo(u), hi = bfhi(u);
    if      (a == 0) { a0[0] += lo; a1[0] += hi; }
    else if (a == 1) { a0[1] += lo; a1[1] += hi; }
    else if (a == 2) { a0[2] += lo; a1[2] += hi; }
    else if (a == 3) { a0[3] += lo; a1[3] += hi; }
    else if (a == 4) { a0[4] += lo; a1[4] += hi; }
    else if (a == 5) { a0[5] += lo; a1[5] += hi; }
    else if (a == 6) { a0[6] += lo; a1[6] += hi; }
    else             { a0[7] += lo; a1[7] += hi; }
  }
  #pragma unroll
  for (int k = 0; k < 8; ++k) {
    accL[half][k][c2*2]   = a0[k];
    accL[half][k][c2*2+1] = a1[k];
  }
  __syncthreads();
  // ---- merge block partials to global (slot-spread to cut atomic contention)
  const int slot = blockIdx.x & 7;
  float* dst = accs + ((size_t)slot*BB + b)*NCLUS*CC;
  #pragma unroll
  for (int i = t*8; i < t*8+8; ++i) {
    float v = ((float*)accL[0])[i] + ((float*)accL[1])[i];
    atomicAdd(&dst[i], v);
  }
  if (t < NCLUS) atomicAdd(&counts[b*NCLUS + t], (float)cntL[t]);
}

// sum slots -> centers ; norm -> cnorm ; re-zero acc slots + counts
__global__ __launch_bounds__(256) void centers_finalize(float* __restrict__ accs,
    float* __restrict__ counts, float* __restrict__ centers, float* __restrict__ cnorm) {
  const int row = blockIdx.x;   // 0..63
  const int t = threadIdx.x;
  float v = 0.0f;
  #pragma unroll
  for (int s = 0; s < 8; ++s) {
    v += accs[((size_t)s*64 + row)*CC + t];
    accs[((size_t)s*64 + row)*CC + t] = 0.0f;
  }
  float cnt = fmaxf(counts[row], 1.0f);
  float c = v / cnt;
  centers[(size_t)row*CC + t] = c;
  float s2 = c*c;
  #pragma unroll
  for (int o = 32; o; o >>= 1) s2 += __shfl_xor(s2, o);
  __shared__ float ps[4];
  if ((t & 63) == 0) ps[t >> 6] = s2;
  __syncthreads();
  float tot = ps[0] + ps[1] + ps[2] + ps[3];
  cnorm[(size_t)row*CC + t] = c * (1.0f / fmaxf(sqrtf(tot), 1e-12f));
  if (t == 0) counts[row] = 0.0f;
}

// t = softmax(10*sim) @ centers + F_p  -> bf16
__global__ __launch_bounds__(256) void final_fuse2(const ushort* __restrict__ nbf,
    const float* __restrict__ F_p, const float* __restrict__ cnorm,
    const float* __restrict__ centers, const float* __restrict__ rnorm,
    ushort* __restrict__ tbf) {
  __shared__ float cnL[NCLUS][CC];
  __shared__ float ceL[NCLUS][CC];
  const int t = threadIdx.x;
  const int b = blockIdx.x >> 6;
  for (int i = t; i < NCLUS*CC; i += 256) {
    ((float*)cnL)[i] = cnorm[(size_t)b*NCLUS*CC + i];
    ((float*)ceL)[i] = centers[(size_t)b*NCLUS*CC + i];
  }
  __syncthreads();
  const size_t p = (size_t)blockIdx.x*256 + t;
  float sims[8];
  compute_sims((const uint4*)(nbf + p*CC), cnL, sims);
  float rn10 = rnorm[p] * 10.0f;
  float m = -1e30f;
  #pragma unroll
  for (int k = 0; k < 8; ++k) { sims[k] *= rn10; m = fmaxf(m, sims[k]); }
  float w[8], sw = 0.0f;
  #pragma unroll
  for (int k = 0; k < 8; ++k) { w[k] = __expf(sims[k] - m); sw += w[k]; }
  float inv = 1.0f / sw;
  #pragma unroll
  for (int k = 0; k < 8; ++k) w[k] *= inv;
  const float* fp = F_p + p*CC;
  ushort* op = tbf + p*CC;
  #pragma unroll 2
  for (int q = 0; q < 32; ++q) {
    float4 f0 = *(const float4*)&fp[q*8];
    float4 f1 = *(const float4*)&fp[q*8+4];
    #pragma unroll
    for (int k = 0; k < 8; ++k) {
      const float4* c = (const float4*)&ceL[k][q*8];
      float4 c0 = c[0], c1 = c[1];
      f0.x = fmaf(w[k], c0.x, f0.x); f0.y = fmaf(w[k], c0.y, f0.y);
      f0.z = fmaf(w[k], c0.z, f0.z); f0.w = fmaf(w[k], c0.w, f0.w);
      f1.x = fmaf(w[k], c1.x, f1.x); f1.y = fmaf(w[k], c1.y, f1.y);
      f1.z = fmaf(w[k], c1.z, f1.z); f1.w = fmaf(w[k], c1.w, f1.w);
    }
    uint4 o;
    o.x = (uint)f2bf(f0.x) | ((uint)f2bf(f0.y) << 16);
    o.y = (uint)f2bf(f0.z) | ((uint)f2bf(f0.w) << 16);
    o.z = (uint)f2bf(f1.x) | ((uint)f2bf(f1.y) << 16);
    o.w = (uint)f2bf(f1.z) | ((uint)f2bf(f1.w) << 16);
    *(uint4*)&op[q*8] = o;
  }
}

extern "C" void kernel_launch(void* const* d_in, const int* in_sizes, int n_in,
                              void* d_out, int out_size, void* d_ws, size_t ws_size,
                              hipStream_t stream) {
  const float* F_p      = (const float*)d_in[0];
  const float* proj_w   = (const float*)d_in[1];
  const float* proj_b   = (const float*)d_in[2];
  const float* refine_w = (const float*)d_in[3];
  const float* refine_b = (const float*)d_in[4];
  float* out = (float*)d_out;

  char* ws = (char*)d_ws;
  ushort* nbf    = (ushort*)ws;                                    // 64 MiB
  ushort* tbf    = (ushort*)(ws + (size_t)BPROWS*CC*2);            // 64 MiB
  float*  rnorm  = (float*)(ws + (size_t)BPROWS*CC*4);             // 512 KiB
  float*  centers= rnorm + BPROWS;
  float*  cnorm  = centers + BB*NCLUS*CC;
  float*  accs   = cnorm + BB*NCLUS*CC;                            // 8 slots
  float*  counts = accs + 8*BB*NCLUS*CC;

  dim3 gg(BPROWS/TILE, CC/TILE);
  gemm_bt<false,true><<<gg, 256, 0, stream>>>(F_p, proj_w, proj_b, nbf);
  rownorm_bf<<<2048, 256, 0, stream>>>(nbf, rnorm);
  init_centers<<<64, 256, 0, stream>>>(nbf, centers);
  center_norm_init<<<64, 256, 0, stream>>>(centers, cnorm, accs, counts);
  for (int it = 0; it < 3; ++it) {
    assign_acc2<<<512, 256, 0, stream>>>(nbf, cnorm, accs, counts);
    centers_finalize<<<64, 256, 0, stream>>>(accs, counts, centers, cnorm);
  }
  final_fuse2<<<512, 256, 0, stream>>>(nbf, F_p, cnorm, centers, rnorm, tbf);
  gemm_bt<true,false><<<gg, 256, 0, stream>>>(tbf, refine_w, refine_b, out);
}

// Round 3
// 446.336 us; speedup vs baseline: 2.7906x; 1.6483x over previous
//
#include <hip/hip_runtime.h>
#include <hip/hip_bf16.h>
#include <cmath>

#define BB 8
#define PP 16384
#define CC 256
#define NCLUS 8
#define BPROWS (BB*PP)

typedef unsigned int uint;
typedef unsigned short ushort;
typedef __bf16 bf16x8 __attribute__((ext_vector_type(8)));
typedef float f32x16 __attribute__((ext_vector_type(16)));

__device__ __forceinline__ float bflo(uint u){ return __uint_as_float(u << 16); }
__device__ __forceinline__ float bfhi(uint u){ return __uint_as_float(u & 0xffff0000u); }
__device__ __forceinline__ ushort f2bf(float x){ __hip_bfloat16 h = __float2bfloat16(x); return *(ushort*)&h; }
__device__ __forceinline__ uint pk2(float a, float b){ return (uint)f2bf(a) | ((uint)f2bf(b) << 16); }

// D = A @ W^T + bias.  A: 131072 x 256 (fp32 if !ABF16, bf16 if ABF16), W: 256x256 fp32 (cvt to bf16).
// PROJ: D written bf16 + per-row rnorm.  !PROJ: D written fp32.
template<bool ABF16, bool PROJ>
__global__ __launch_bounds__(512) void gemm_mfma(const void* __restrict__ Av,
    const float* __restrict__ W, const float* __restrict__ bias,
    void* __restrict__ Dv, float* __restrict__ rnorm) {
  __shared__ __align__(16) char AlB[128*64*2];   // 16 KB, swizzled bf16 A tile
  __shared__ __align__(16) char WlB[256*64*2];   // 32 KB, swizzled bf16 W tile
  __shared__ float rnp[128][4];
  const int t  = threadIdx.x;
  const int p0 = blockIdx.x * 128;
  const int lane = t & 63;
  const int w  = t >> 6;
  const int wr = w >> 2, wc = w & 3;

  // --- staging maps (chunk = 16B of bf16 = 8 elems) ---
  int aoff[2]; size_t agb[2];
  #pragma unroll
  for (int i = 0; i < 2; ++i) {
    int c = t + i*512, row = c >> 3, cc = c & 7;
    aoff[i] = row*128 + ((cc*16) ^ ((row & 7) << 4));
    agb[i]  = (size_t)(p0 + row)*CC + cc*8;
  }
  int woff[4]; size_t wgb[4];
  #pragma unroll
  for (int i = 0; i < 4; ++i) {
    int c = t + i*512, row = c >> 3, cc = c & 7;
    woff[i] = row*128 + ((cc*16) ^ ((row & 7) << 4));
    wgb[i]  = (size_t)row*CC + cc*8;
  }
  const int arow = (wr << 6) + (lane & 31);
  const int brow = (wc << 6) + (lane & 31);
  const int kb0  = (lane >> 5) << 4;

  uint4 ra[2], rw[4];
  auto LOADA = [&](int ks) {
    #pragma unroll
    for (int i = 0; i < 2; ++i) {
      if constexpr (ABF16) {
        ra[i] = *(const uint4*)((const ushort*)Av + agb[i] + ks*64);
      } else {
        const float* A = (const float*)Av;
        float4 v0 = *(const float4*)(A + agb[i] + ks*64);
        float4 v1 = *(const float4*)(A + agb[i] + ks*64 + 4);
        ra[i] = make_uint4(pk2(v0.x,v0.y), pk2(v0.z,v0.w), pk2(v1.x,v1.y), pk2(v1.z,v1.w));
      }
    }
  };
  auto LOADW = [&](int ks) {
    #pragma unroll
    for (int i = 0; i < 4; ++i) {
      float4 v0 = *(const float4*)(W + wgb[i] + ks*64);
      float4 v1 = *(const float4*)(W + wgb[i] + ks*64 + 4);
      rw[i] = make_uint4(pk2(v0.x,v0.y), pk2(v0.z,v0.w), pk2(v1.x,v1.y), pk2(v1.z,v1.w));
    }
  };
  auto WRITE = [&]() {
    #pragma unroll
    for (int i = 0; i < 2; ++i) *(uint4*)(AlB + aoff[i]) = ra[i];
    #pragma unroll
    for (int i = 0; i < 4; ++i) *(uint4*)(WlB + woff[i]) = rw[i];
  };

  f32x16 acc[2][2];
  #pragma unroll
  for (int fm = 0; fm < 2; ++fm)
    #pragma unroll
    for (int fn = 0; fn < 2; ++fn)
      #pragma unroll
      for (int r = 0; r < 16; ++r) acc[fm][fn][r] = 0.0f;

  LOADA(0); LOADW(0);
  WRITE();
  __syncthreads();

  #pragma unroll
  for (int ks = 0; ks < 4; ++ks) {
    if (ks < 3) { LOADA(ks+1); LOADW(ks+1); }   // in flight under ds_read+MFMA
    bf16x8 af[2][4], bg[2][4];
    #pragma unroll
    for (int fm = 0; fm < 2; ++fm)
      #pragma unroll
      for (int kq = 0; kq < 4; ++kq) {
        int row = arow + (fm << 5);
        int off = row*128 + (((kq << 5) + kb0) ^ ((row & 7) << 4));
        af[fm][kq] = *(const bf16x8*)(AlB + off);
      }
    #pragma unroll
    for (int fn = 0; fn < 2; ++fn)
      #pragma unroll
      for (int kq = 0; kq < 4; ++kq) {
        int row = brow + (fn << 5);
        int off = row*128 + (((kq << 5) + kb0) ^ ((row & 7) << 4));
        bg[fn][kq] = *(const bf16x8*)(WlB + off);
      }
    #pragma unroll
    for (int kq = 0; kq < 4; ++kq)
      #pragma unroll
      for (int fm = 0; fm < 2; ++fm)
        #pragma unroll
        for (int fn = 0; fn < 2; ++fn)
          acc[fm][fn] = __builtin_amdgcn_mfma_f32_32x32x16_bf16(
              af[fm][kq], bg[fn][kq], acc[fm][fn], 0, 0, 0);
    __syncthreads();
    if (ks < 3) { WRITE(); __syncthreads(); }
  }

  // --- epilogue ---
  const int colb = (wc << 6) + (lane & 31);
  const float b0 = bias[colb], b1 = bias[colb + 32];
  #pragma unroll
  for (int fm = 0; fm < 2; ++fm) {
    float rs[16];
    #pragma unroll
    for (int r = 0; r < 16; ++r) {
      int rowin = (r & 3) + ((r >> 2) << 3) + ((lane >> 5) << 2);
      size_t grow = (size_t)(p0 + (wr << 6) + (fm << 5) + rowin);
      float v0 = acc[fm][0][r] + b0;
      float v1 = acc[fm][1][r] + b1;
      if constexpr (PROJ) {
        ushort* D = (ushort*)Dv;
        D[grow*CC + colb]      = f2bf(v0);
        D[grow*CC + colb + 32] = f2bf(v1);
        rs[r] = v0*v0 + v1*v1;
      } else {
        float* D = (float*)Dv;
        D[grow*CC + colb]      = v0;
        D[grow*CC + colb + 32] = v1;
      }
    }
    if constexpr (PROJ) {
      #pragma unroll
      for (int m = 1; m < 32; m <<= 1)
        #pragma unroll
        for (int r = 0; r < 16; ++r) rs[r] += __shfl_xor(rs[r], m);
      if ((lane & 31) == 0) {
        #pragma unroll
        for (int r = 0; r < 16; ++r) {
          int rowin = (r & 3) + ((r >> 2) << 3) + ((lane >> 5) << 2);
          rnp[(wr << 6) + (fm << 5) + rowin][wc] = rs[r];
        }
      }
    }
  }
  if constexpr (PROJ) {
    __syncthreads();
    if (t < 128) {
      float s = rnp[t][0] + rnp[t][1] + rnp[t][2] + rnp[t][3];
      rnorm[p0 + t] = 1.0f / fmaxf(sqrtf(s), 1e-12f);
    }
  }
}

__global__ void init_centers(const ushort* __restrict__ nbf, float* __restrict__ centers) {
  const int idx[8] = {0, 2340, 4680, 7021, 9361, 11702, 14042, 16383};
  int b = blockIdx.x >> 3, k = blockIdx.x & 7;
  int c = threadIdx.x;
  centers[(size_t)(b*NCLUS + k)*CC + c] =
      __uint_as_float(((uint)nbf[((size_t)b*PP + idx[k])*CC + c]) << 16);
}

__global__ __launch_bounds__(256) void center_norm_init(const float* __restrict__ centers,
    float* __restrict__ cnorm, float* __restrict__ accs, float* __restrict__ counts) {
  const int row = blockIdx.x;
  const int t = threadIdx.x;
  float c = centers[(size_t)row*CC + t];
  float s2 = c*c;
  #pragma unroll
  for (int o = 32; o; o >>= 1) s2 += __shfl_xor(s2, o);
  __shared__ float ps[4];
  if ((t & 63) == 0) ps[t >> 6] = s2;
  __syncthreads();
  float tot = ps[0] + ps[1] + ps[2] + ps[3];
  cnorm[(size_t)row*CC + t] = c * (1.0f / fmaxf(sqrtf(tot), 1e-12f));
  #pragma unroll
  for (int s = 0; s < 8; ++s) accs[((size_t)s*64 + row)*CC + t] = 0.0f;
  if (t == 0) counts[row] = 0.0f;
}

__device__ __forceinline__ void compute_sims(const uint4* __restrict__ rp,
                                             const float (*cnL)[CC], float* sims) {
  #pragma unroll
  for (int k = 0; k < 8; ++k) sims[k] = 0.0f;
  #pragma unroll 4
  for (int q = 0; q < 32; ++q) {
    uint4 u = rp[q];
    float v0 = bflo(u.x), v1 = bfhi(u.x), v2 = bflo(u.y), v3 = bfhi(u.y);
    float v4 = bflo(u.z), v5 = bfhi(u.z), v6 = bflo(u.w), v7 = bfhi(u.w);
    #pragma unroll
    for (int k = 0; k < 8; ++k) {
      const float4* c = (const float4*)&cnL[k][q*8];
      float4 c0 = c[0], c1 = c[1];
      sims[k] += v0*c0.x + v1*c0.y + v2*c0.z + v3*c0.w
               + v4*c1.x + v5*c1.y + v6*c1.z + v7*c1.w;
    }
  }
}

__global__ __launch_bounds__(256) void assign_acc2(const ushort* __restrict__ nbf,
    const float* __restrict__ cnorm, float* __restrict__ accs, float* __restrict__ counts) {
  __shared__ float cnL[NCLUS][CC];
  __shared__ float accL[2][NCLUS][CC];
  __shared__ int assignL[256];
  __shared__ int cntL[NCLUS];
  const int t = threadIdx.x;
  const int b = blockIdx.x >> 6;
  for (int i = t; i < NCLUS*CC; i += 256)
    ((float*)cnL)[i] = cnorm[(size_t)b*NCLUS*CC + i];
  if (t < NCLUS) cntL[t] = 0;
  __syncthreads();
  const size_t p = (size_t)blockIdx.x*256 + t;
  float sims[8];
  compute_sims((const uint4*)(nbf + p*CC), cnL, sims);
  int best = 0; float bs = sims[0];
  #pragma unroll
  for (int k = 1; k < 8; ++k) if (sims[k] > bs) { bs = sims[k]; best = k; }
  assignL[t] = best;
  atomicAdd(&cntL[best], 1);
  __syncthreads();
  const int c2   = t & 127;
  const int half = t >> 7;
  float a0[8] = {0,0,0,0,0,0,0,0}, a1[8] = {0,0,0,0,0,0,0,0};
  const ushort* base = nbf + ((size_t)blockIdx.x*256 + half*128)*CC;
  #pragma unroll 4
  for (int i = 0; i < 128; ++i) {
    int a = __builtin_amdgcn_readfirstlane(assignL[half*128 + i]);
    uint u = *(const uint*)(base + (size_t)i*CC + c2*2);
    float lo = bflo(u), hi = bfhi(u);
    if      (a == 0) { a0[0] += lo; a1[0] += hi; }
    else if (a == 1) { a0[1] += lo; a1[1] += hi; }
    else if (a == 2) { a0[2] += lo; a1[2] += hi; }
    else if (a == 3) { a0[3] += lo; a1[3] += hi; }
    else if (a == 4) { a0[4] += lo; a1[4] += hi; }
    else if (a == 5) { a0[5] += lo; a1[5] += hi; }
    else if (a == 6) { a0[6] += lo; a1[6] += hi; }
    else             { a0[7] += lo; a1[7] += hi; }
  }
  #pragma unroll
  for (int k = 0; k < 8; ++k) {
    accL[half][k][c2*2]   = a0[k];
    accL[half][k][c2*2+1] = a1[k];
  }
  __syncthreads();
  const int slot = blockIdx.x & 7;
  float* dst = accs + ((size_t)slot*BB + b)*NCLUS*CC;
  #pragma unroll
  for (int i = t*8; i < t*8+8; ++i) {
    float v = ((float*)accL[0])[i] + ((float*)accL[1])[i];
    atomicAdd(&dst[i], v);
  }
  if (t < NCLUS) atomicAdd(&counts[b*NCLUS + t], (float)cntL[t]);
}

__global__ __launch_bounds__(256) void centers_finalize(float* __restrict__ accs,
    float* __restrict__ counts, float* __restrict__ centers, float* __restrict__ cnorm) {
  const int row = blockIdx.x;
  const int t = threadIdx.x;
  float v = 0.0f;
  #pragma unroll
  for (int s = 0; s < 8; ++s) {
    v += accs[((size_t)s*64 + row)*CC + t];
    accs[((size_t)s*64 + row)*CC + t] = 0.0f;
  }
  float cnt = fmaxf(counts[row], 1.0f);
  float c = v / cnt;
  centers[(size_t)row*CC + t] = c;
  float s2 = c*c;
  #pragma unroll
  for (int o = 32; o; o >>= 1) s2 += __shfl_xor(s2, o);
  __shared__ float ps[4];
  if ((t & 63) == 0) ps[t >> 6] = s2;
  __syncthreads();
  float tot = ps[0] + ps[1] + ps[2] + ps[3];
  cnorm[(size_t)row*CC + t] = c * (1.0f / fmaxf(sqrtf(tot), 1e-12f));
  if (t == 0) counts[row] = 0.0f;
}

__global__ __launch_bounds__(256) void final_fuse2(const ushort* __restrict__ nbf,
    const float* __restrict__ F_p, const float* __restrict__ cnorm,
    const float* __restrict__ centers, const float* __restrict__ rnorm,
    ushort* __restrict__ tbf) {
  __shared__ float cnL[NCLUS][CC];
  __shared__ float ceL[NCLUS][CC];
  const int t = threadIdx.x;
  const int b = blockIdx.x >> 6;
  for (int i = t; i < NCLUS*CC; i += 256) {
    ((float*)cnL)[i] = cnorm[(size_t)b*NCLUS*CC + i];
    ((float*)ceL)[i] = centers[(size_t)b*NCLUS*CC + i];
  }
  __syncthreads();
  const size_t p = (size_t)blockIdx.x*256 + t;
  float sims[8];
  compute_sims((const uint4*)(nbf + p*CC), cnL, sims);
  float rn10 = rnorm[p] * 10.0f;
  float m = -1e30f;
  #pragma unroll
  for (int k = 0; k < 8; ++k) { sims[k] *= rn10; m = fmaxf(m, sims[k]); }
  float w[8], sw = 0.0f;
  #pragma unroll
  for (int k = 0; k < 8; ++k) { w[k] = __expf(sims[k] - m); sw += w[k]; }
  float inv = 1.0f / sw;
  #pragma unroll
  for (int k = 0; k < 8; ++k) w[k] *= inv;
  const float* fp = F_p + p*CC;
  ushort* op = tbf + p*CC;
  #pragma unroll 2
  for (int q = 0; q < 32; ++q) {
    float4 f0 = *(const float4*)&fp[q*8];
    float4 f1 = *(const float4*)&fp[q*8+4];
    #pragma unroll
    for (int k = 0; k < 8; ++k) {
      const float4* c = (const float4*)&ceL[k][q*8];
      float4 c0 = c[0], c1 = c[1];
      f0.x = fmaf(w[k], c0.x, f0.x); f0.y = fmaf(w[k], c0.y, f0.y);
      f0.z = fmaf(w[k], c0.z, f0.z); f0.w = fmaf(w[k], c0.w, f0.w);
      f1.x = fmaf(w[k], c1.x, f1.x); f1.y = fmaf(w[k], c1.y, f1.y);
      f1.z = fmaf(w[k], c1.z, f1.z); f1.w = fmaf(w[k], c1.w, f1.w);
    }
    uint4 o;
    o.x = (uint)f2bf(f0.x) | ((uint)f2bf(f0.y) << 16);
    o.y = (uint)f2bf(f0.z) | ((uint)f2bf(f0.w) << 16);
    o.z = (uint)f2bf(f1.x) | ((uint)f2bf(f1.y) << 16);
    o.w = (uint)f2bf(f1.z) | ((uint)f2bf(f1.w) << 16);
    *(uint4*)&op[q*8] = o;
  }
}

extern "C" void kernel_launch(void* const* d_in, const int* in_sizes, int n_in,
                              void* d_out, int out_size, void* d_ws, size_t ws_size,
                              hipStream_t stream) {
  const float* F_p      = (const float*)d_in[0];
  const float* proj_w   = (const float*)d_in[1];
  const float* proj_b   = (const float*)d_in[2];
  const float* refine_w = (const float*)d_in[3];
  const float* refine_b = (const float*)d_in[4];
  float* out = (float*)d_out;

  char* ws = (char*)d_ws;
  ushort* nbf    = (ushort*)ws;                                    // 64 MiB
  ushort* tbf    = (ushort*)(ws + (size_t)BPROWS*CC*2);            // 64 MiB
  float*  rnorm  = (float*)(ws + (size_t)BPROWS*CC*4);             // 512 KiB
  float*  centers= rnorm + BPROWS;
  float*  cnorm  = centers + BB*NCLUS*CC;
  float*  accs   = cnorm + BB*NCLUS*CC;                            // 8 slots
  float*  counts = accs + 8*BB*NCLUS*CC;

  gemm_mfma<false, true><<<1024, 512, 0, stream>>>(F_p, proj_w, proj_b, nbf, rnorm);
  init_centers<<<64, 256, 0, stream>>>(nbf, centers);
  center_norm_init<<<64, 256, 0, stream>>>(centers, cnorm, accs, counts);
  for (int it = 0; it < 3; ++it) {
    assign_acc2<<<512, 256, 0, stream>>>(nbf, cnorm, accs, counts);
    centers_finalize<<<64, 256, 0, stream>>>(accs, counts, centers, cnorm);
  }
  final_fuse2<<<512, 256, 0, stream>>>(nbf, F_p, cnorm, centers, rnorm, tbf);
  gemm_mfma<true, false><<<1024, 512, 0, stream>>>(tbf, refine_w, refine_b, out, nullptr);
}